// Round 1
// baseline (4740.776 us; speedup 1.0000x reference)
//
#include <hip/hip_runtime.h>
#include <hip/hip_cooperative_groups.h>
#include <cstdint>
#include <cstddef>

namespace cg = cooperative_groups;

// Problem dims
#define NB    64      // batch
#define SENC  64      // encoder steps
#define TDEC  31      // decoder steps (tgt[:, :-1])
#define EDIM  256
#define HDIM  512
#define VOCAB 32000
#define MROWS (NB * TDEC)   // 1984
#define MPAD  2048

// workspace byte offsets
#define OFF_HTA  0
#define OFF_HTB  (OFF_HTA + HDIM * NB * 4)
#define OFF_XPE  (OFF_HTB + HDIM * NB * 4)
#define OFF_XPD  (OFF_XPE + 256 * SENC * 8 * NB * 4)
#define OFF_HS   (OFF_XPD + 256 * TDEC * 8 * NB * 4)
#define OFF_FCW  (OFF_HS + MPAD * HDIM * 2)

typedef __attribute__((ext_vector_type(8))) short bf16x8;   // 8 bf16 (4 VGPRs)
typedef __attribute__((ext_vector_type(4))) float f32x4;

__device__ __forceinline__ float sigf(float x) { return 1.0f / (1.0f + __expf(-x)); }
__device__ __forceinline__ float tanhfast(float x) {
  // tanh(x) = 1 - 2/(e^{2x}+1); saturates correctly at +-inf
  return 1.0f - 2.0f / (__expf(2.0f * x) + 1.0f);
}
__device__ __forceinline__ unsigned short f2bf(float x) {
  unsigned int u = __float_as_uint(x);
  u += 0x7fffu + ((u >> 16) & 1u);   // RNE
  return (unsigned short)(u >> 16);
}

struct CoopParams {
  const int* src; const int* tgt;
  const float* enc_emb; const float* dec_emb;
  const float* enc_Wih; const float* enc_Whh; const float* enc_bih; const float* enc_bhh;
  const float* dec_Wih; const float* dec_Whh; const float* dec_bih; const float* dec_bhh;
  const float* fc_W;
  float* hTA; float* hTB; float* xpe; float* xpd;
  unsigned short* hs; unsigned short* fcw;
};

// Input projection: xp[s][r][b] = bias_r + sum_e Wih[row_g(r)][e] * emb[idx[b][s]][e]
// Block owns 8 gate rows (2 hidden units). Waves split E; partial-reduce via LDS.
__device__ void xp_phase(const int* idxmat, int istride, int S,
                         const float* emb, const float* Wih,
                         const float* bih, const float* bhh,
                         float* xp_out, int bid, int tid,
                         float* W_lds, float* pbuf, float* bias_lds) {
  const int lane = tid & 63;
  const int w = tid >> 6;
  // load Wih slice: 8 rows x 256
  {
    int r = tid >> 5;                  // 0..7
    int e0 = (tid & 31) * 8;           // 0..248
    int row_g = (r >> 1) * HDIM + bid * 2 + (r & 1);
    const float* sp = Wih + (size_t)row_g * EDIM + e0;
    *(float4*)&W_lds[r * HDIM + e0]     = *(const float4*)sp;
    *(float4*)&W_lds[r * HDIM + e0 + 4] = *(const float4*)(sp + 4);
    if (tid < 8) {
      int rg = (tid >> 1) * HDIM + bid * 2 + (tid & 1);
      bias_lds[tid] = bih[rg] + bhh[rg];
    }
  }
  __syncthreads();
  for (int s = 0; s < S; ++s) {
    int idx = idxmat[lane * istride + s];
    const float* xrow = emb + (size_t)idx * EDIM;
    float acc[8];
#pragma unroll
    for (int r = 0; r < 8; ++r) acc[r] = 0.0f;
    for (int e = w * 64; e < w * 64 + 64; e += 4) {
      float4 xv = *(const float4*)&xrow[e];
#pragma unroll
      for (int r = 0; r < 8; ++r) {
        float4 wv = *(const float4*)&W_lds[r * HDIM + e];
        acc[r] += wv.x * xv.x + wv.y * xv.y + wv.z * xv.z + wv.w * xv.w;
      }
    }
#pragma unroll
    for (int r = 0; r < 8; ++r) pbuf[(w * 8 + r) * 64 + lane] = acc[r];
    __syncthreads();
    if (tid < 128) {
      int unit = tid >> 6, b = tid & 63;
#pragma unroll
      for (int gate = 0; gate < 4; ++gate) {
        int r = gate * 2 + unit;
        float v = bias_lds[r];
#pragma unroll
        for (int ww = 0; ww < 4; ++ww) v += pbuf[(ww * 8 + r) * 64 + b];
        xp_out[((size_t)(bid * S + s) * 8 + r) * 64 + b] = v;
      }
    }
    __syncthreads();
  }
}

// Recurrence: per step gates[r][b] = xp + sum_k Whh[row_g(r)][k] * h_prev[k][b]
// hT layout [k][b] so lane=b reads are coalesced. Waves split K, reduce via LDS.
__device__ void recur_phase(const float* Whh, const float* xp, int S,
                            int bid, int tid,
                            float* W_lds, float* pbuf, float* c_lds,
                            float*& hp, float*& hn,
                            unsigned short* hs_or_null,
                            cg::grid_group& grid) {
  const int lane = tid & 63;
  const int w = tid >> 6;
  const int j0 = bid * 2;
  // load Whh slice: 8 rows x 512
  {
    int r = tid >> 5;
    int e0 = (tid & 31) * 16;
    int row_g = (r >> 1) * HDIM + j0 + (r & 1);
    const float* sp = Whh + (size_t)row_g * HDIM + e0;
#pragma unroll
    for (int q = 0; q < 4; ++q)
      *(float4*)&W_lds[r * HDIM + e0 + q * 4] = *(const float4*)(sp + q * 4);
  }
  __syncthreads();
  for (int s = 0; s < S; ++s) {
    const float* hpw = hp + (size_t)w * 128 * 64;
    float acc[8];
#pragma unroll
    for (int r = 0; r < 8; ++r) acc[r] = 0.0f;
    for (int kk = 0; kk < 128; kk += 4) {
      float h0 = hpw[(kk + 0) * 64 + lane];
      float h1 = hpw[(kk + 1) * 64 + lane];
      float h2 = hpw[(kk + 2) * 64 + lane];
      float h3 = hpw[(kk + 3) * 64 + lane];
#pragma unroll
      for (int r = 0; r < 8; ++r) {
        float4 wv = *(const float4*)&W_lds[r * HDIM + w * 128 + kk];
        acc[r] += wv.x * h0 + wv.y * h1 + wv.z * h2 + wv.w * h3;
      }
    }
#pragma unroll
    for (int r = 0; r < 8; ++r) pbuf[(w * 8 + r) * 64 + lane] = acc[r];
    __syncthreads();
    if (tid < 128) {
      int unit = tid >> 6, b = tid & 63;
      float g[4];
#pragma unroll
      for (int gate = 0; gate < 4; ++gate) {
        int r = gate * 2 + unit;
        float v = xp[((size_t)(bid * S + s) * 8 + r) * 64 + b];
#pragma unroll
        for (int ww = 0; ww < 4; ++ww) v += pbuf[(ww * 8 + r) * 64 + b];
        g[gate] = v;
      }
      float c = c_lds[unit * 64 + b];
      float iv = sigf(g[0]), fv = sigf(g[1]);
      float gv = tanhfast(g[2]), ov = sigf(g[3]);
      c = fv * c + iv * gv;
      float h = ov * tanhfast(c);
      c_lds[unit * 64 + b] = c;
      hn[(j0 + unit) * 64 + b] = h;
      if (hs_or_null)
        hs_or_null[((size_t)b * TDEC + s) * HDIM + j0 + unit] = f2bf(h);
    }
    grid.sync();
    float* tmp = hp; hp = hn; hn = tmp;
  }
}

__global__ __launch_bounds__(256, 1) void lstm_coop(CoopParams p) {
  cg::grid_group grid = cg::this_grid();
  __shared__ __align__(16) float W_lds[8 * HDIM];     // 16 KB
  __shared__ float pbuf[32 * 64];                     // 8 KB
  __shared__ float c_lds[2 * 64];
  __shared__ float bias_lds[8];
  const int tid = threadIdx.x;
  const int bid = blockIdx.x;

  // ---- setup: zero h0, zero hs pad rows, convert fc_W -> bf16 ----
  {
    int gtid = bid * 256 + tid;
    for (int i = gtid; i < HDIM * NB; i += 65536) p.hTA[i] = 0.0f;
    for (int i = gtid; i < (MPAD - MROWS) * HDIM; i += 65536) p.hs[MROWS * HDIM + i] = 0;
    for (int i = gtid; i < VOCAB * HDIM; i += 65536) p.fcw[i] = f2bf(p.fc_W[i]);
  }

  // ---- xp projections (block-private, no grid sync needed) ----
  xp_phase(p.src, SENC, SENC, p.enc_emb, p.enc_Wih, p.enc_bih, p.enc_bhh,
           p.xpe, bid, tid, W_lds, pbuf, bias_lds);
  __syncthreads();
  xp_phase(p.tgt, 32, TDEC, p.dec_emb, p.dec_Wih, p.dec_bih, p.dec_bhh,
           p.xpd, bid, tid, W_lds, pbuf, bias_lds);
  __syncthreads();

  if (tid < 128) c_lds[tid] = 0.0f;

  grid.sync();   // hTA zero visible to all blocks

  float* hp = p.hTA;
  float* hn = p.hTB;
  recur_phase(p.enc_Whh, p.xpe, SENC, bid, tid, W_lds, pbuf, c_lds, hp, hn, nullptr, grid);
  recur_phase(p.dec_Whh, p.xpd, TDEC, bid, tid, W_lds, pbuf, c_lds, hp, hn, p.hs, grid);
}

// out[b][0][:] = 0
__global__ void zero_plane(float* __restrict__ out) {
  int i = blockIdx.x * blockDim.x + threadIdx.x;
  if (i < NB * (VOCAB / 4)) {
    int b = i / (VOCAB / 4);
    int q = i - b * (VOCAB / 4);
    ((float4*)out)[(size_t)b * (32 * (VOCAB / 4)) + q] = make_float4(0.f, 0.f, 0.f, 0.f);
  }
}

// logits[m][n] = sum_k hs[m][k]*fcw[n][k] + fc_b[n]; out[b][t+1][n], m = b*31+t
__global__ __launch_bounds__(256) void fc_gemm(const unsigned short* __restrict__ A,
                                               const unsigned short* __restrict__ Bm,
                                               const float* __restrict__ bias,
                                               float* __restrict__ out) {
  __shared__ __align__(16) unsigned short As[128 * 32];
  __shared__ __align__(16) unsigned short Bs[128 * 32];
  const int tid = threadIdx.x;
  const int lane = tid & 63;
  const int w = tid >> 6;
  const int m0 = blockIdx.y * 128;
  const int n0 = blockIdx.x * 128;
  const int wm = (w >> 1) * 64;
  const int wn = (w & 1) * 64;
  const int ml = lane & 15;
  const int kq = (lane >> 4) * 8;

  f32x4 acc[4][4] = {};

  for (int k0 = 0; k0 < HDIM; k0 += 32) {
    for (int c = tid; c < 512; c += 256) {      // 2 iterations: stage 128x32 A and B tiles
      int row = c >> 2;
      int ko = (c & 3) * 8;
      *(uint4*)&As[c * 8] = *(const uint4*)(A + (size_t)(m0 + row) * HDIM + k0 + ko);
      *(uint4*)&Bs[c * 8] = *(const uint4*)(Bm + (size_t)(n0 + row) * HDIM + k0 + ko);
    }
    __syncthreads();
    bf16x8 fa[4], fb[4];
#pragma unroll
    for (int i = 0; i < 4; ++i)
      fa[i] = *(const bf16x8*)&As[(wm + 16 * i + ml) * 32 + kq];
#pragma unroll
    for (int j = 0; j < 4; ++j)
      fb[j] = *(const bf16x8*)&Bs[(wn + 16 * j + ml) * 32 + kq];
#pragma unroll
    for (int i = 0; i < 4; ++i)
#pragma unroll
      for (int j = 0; j < 4; ++j)
        acc[i][j] = __builtin_amdgcn_mfma_f32_16x16x32_bf16(fa[i], fb[j], acc[i][j], 0, 0, 0);
    __syncthreads();
  }

  const int rq = (lane >> 4) * 4;
#pragma unroll
  for (int j = 0; j < 4; ++j) {
    int n = n0 + wn + 16 * j + ml;
    float bv = bias[n];
#pragma unroll
    for (int i = 0; i < 4; ++i) {
#pragma unroll
      for (int r = 0; r < 4; ++r) {
        int m = m0 + wm + 16 * i + rq + r;
        if (m < MROWS) {
          int b = m / TDEC;
          int t = m - b * TDEC;
          out[((size_t)(b * 32 + t + 1)) * VOCAB + n] = acc[i][j][r] + bv;
        }
      }
    }
  }
}

extern "C" void kernel_launch(void* const* d_in, const int* in_sizes, int n_in,
                              void* d_out, int out_size, void* d_ws, size_t ws_size,
                              hipStream_t stream) {
  (void)in_sizes; (void)n_in; (void)out_size; (void)ws_size;
  CoopParams p;
  p.src     = (const int*)d_in[0];
  p.tgt     = (const int*)d_in[1];
  p.enc_emb = (const float*)d_in[2];
  p.dec_emb = (const float*)d_in[3];
  p.enc_Wih = (const float*)d_in[4];
  p.enc_Whh = (const float*)d_in[5];
  p.enc_bih = (const float*)d_in[6];
  p.enc_bhh = (const float*)d_in[7];
  p.dec_Wih = (const float*)d_in[8];
  p.dec_Whh = (const float*)d_in[9];
  p.dec_bih = (const float*)d_in[10];
  p.dec_bhh = (const float*)d_in[11];
  p.fc_W    = (const float*)d_in[12];
  const float* fcb = (const float*)d_in[13];
  char* ws = (char*)d_ws;
  p.hTA = (float*)(ws + OFF_HTA);
  p.hTB = (float*)(ws + OFF_HTB);
  p.xpe = (float*)(ws + OFF_XPE);
  p.xpd = (float*)(ws + OFF_XPD);
  p.hs  = (unsigned short*)(ws + OFF_HS);
  p.fcw = (unsigned short*)(ws + OFF_FCW);
  float* out = (float*)d_out;

  void* args[] = { &p };
  hipLaunchCooperativeKernel((const void*)lstm_coop, dim3(256), dim3(256), args, 0, stream);

  hipLaunchKernelGGL(zero_plane, dim3((NB * (VOCAB / 4) + 255) / 256), dim3(256), 0, stream, out);
  hipLaunchKernelGGL(fc_gemm, dim3(VOCAB / 128, MPAD / 128), dim3(256), 0, stream,
                     p.hs, p.fcw, fcb, out);
}

// Round 2
// 3040.367 us; speedup vs baseline: 1.5593x; 1.5593x over previous
//
#include <hip/hip_runtime.h>
#include <cstdint>
#include <cstddef>

// Problem dims
#define NB    64      // batch
#define SENC  64      // encoder steps
#define TDEC  31      // decoder steps (tgt[:, :-1])
#define EDIM  256
#define HDIM  512
#define VOCAB 32000
#define MROWS (NB * TDEC)   // 1984
#define MPAD  2048
#define NBLK  256           // recurrence grid (cooperative)

// workspace byte offsets
#define OFF_HTA  0
#define OFF_HTB  (OFF_HTA + HDIM * NB * 4)
#define OFF_XPE  (OFF_HTB + HDIM * NB * 4)
#define OFF_XPD  (OFF_XPE + 256 * SENC * 8 * NB * 4)
#define OFF_HS   (OFF_XPD + 256 * TDEC * 8 * NB * 4)
#define OFF_FCW  (OFF_HS + MPAD * HDIM * 2)
// barrier counter overlays the first 4 bytes of the hs PAD rows (rows
// MROWS..MPAD-1). Those rows only feed fc_gemm output rows m>=MROWS, which are
// discarded by the m<MROWS guard — garbage there is harmless.

typedef __attribute__((ext_vector_type(8))) short bf16x8;   // 8 bf16 (4 VGPRs)
typedef __attribute__((ext_vector_type(4))) float f32x4;

__device__ __forceinline__ float sigf(float x) { return 1.0f / (1.0f + __expf(-x)); }
__device__ __forceinline__ float tanhfast(float x) {
  return 1.0f - 2.0f / (__expf(2.0f * x) + 1.0f);
}
__device__ __forceinline__ unsigned short f2bf(float x) {
  unsigned int u = __float_as_uint(x);
  u += 0x7fffu + ((u >> 16) & 1u);   // RNE
  return (unsigned short)(u >> 16);
}
__device__ __forceinline__ unsigned pack2(float a, float b) {
  return (unsigned)f2bf(a) | ((unsigned)f2bf(b) << 16);
}

// ---------------- setup: fcw bf16 convert + zeros ----------------
__global__ __launch_bounds__(256) void setup_k(const float* __restrict__ fc_W,
                                               unsigned short* __restrict__ fcw,
                                               float* __restrict__ hTA,
                                               unsigned short* __restrict__ hs,
                                               float* __restrict__ out) {
  const int gt = blockIdx.x * 256 + threadIdx.x;
  const int GSZ = 2048 * 256;
  const float4* s4 = (const float4*)fc_W;
  uint4* d4 = (uint4*)fcw;
  for (int i = gt; i < (VOCAB * HDIM / 8); i += GSZ) {
    float4 x = s4[2 * i], y = s4[2 * i + 1];
    uint4 v;
    v.x = pack2(x.x, x.y); v.y = pack2(x.z, x.w);
    v.z = pack2(y.x, y.y); v.w = pack2(y.z, y.w);
    d4[i] = v;
  }
  float4 z4 = make_float4(0.f, 0.f, 0.f, 0.f);
  // out[:,0,:] = 0
  for (int j = gt; j < NB * (VOCAB / 4); j += GSZ) {
    int b = j / (VOCAB / 4), q = j - b * (VOCAB / 4);
    ((float4*)out)[(size_t)b * (32 * (VOCAB / 4)) + q] = z4;
  }
  if (gt < HDIM * NB / 4) ((float4*)hTA)[gt] = z4;
  // hs pad rows (also zeroes the overlaid barrier counter)
  if (gt < (MPAD - MROWS) * HDIM / 8) {
    uint4 uz = {0u, 0u, 0u, 0u};
    ((uint4*)(hs + (size_t)MROWS * HDIM))[gt] = uz;
  }
}

// ---------------- xp: input projections ----------------
// xp[s][r][b] = bias_r + sum_e Wih[row_g(r)][e] * emb[idx[b][s]][e]
__device__ void xp_phase(const int* idxmat, int istride, int S,
                         const float* emb, const float* Wih,
                         const float* bih, const float* bhh,
                         float* xp_out, int bid, int tid,
                         float* W_lds, float* pbuf, float* bias_lds) {
  const int lane = tid & 63;
  const int w = tid >> 6;
  {
    int r = tid >> 5;                  // 0..7
    int e0 = (tid & 31) * 8;           // 0..248
    int row_g = (r >> 1) * HDIM + bid * 2 + (r & 1);
    const float* sp = Wih + (size_t)row_g * EDIM + e0;
    *(float4*)&W_lds[r * EDIM + e0]     = *(const float4*)sp;
    *(float4*)&W_lds[r * EDIM + e0 + 4] = *(const float4*)(sp + 4);
    if (tid < 8) {
      int rg = (tid >> 1) * HDIM + bid * 2 + (tid & 1);
      bias_lds[tid] = bih[rg] + bhh[rg];
    }
  }
  __syncthreads();
  for (int s = 0; s < S; ++s) {
    int idx = idxmat[lane * istride + s];
    const float* xrow = emb + (size_t)idx * EDIM;
    float acc[8];
#pragma unroll
    for (int r = 0; r < 8; ++r) acc[r] = 0.0f;
    for (int e = w * 64; e < w * 64 + 64; e += 4) {
      float4 xv = *(const float4*)&xrow[e];
#pragma unroll
      for (int r = 0; r < 8; ++r) {
        float4 wv = *(const float4*)&W_lds[r * EDIM + e];
        acc[r] += wv.x * xv.x + wv.y * xv.y + wv.z * xv.z + wv.w * xv.w;
      }
    }
#pragma unroll
    for (int r = 0; r < 8; ++r) pbuf[(w * 8 + r) * 64 + lane] = acc[r];
    __syncthreads();
    if (tid < 128) {
      int unit = tid >> 6, b = tid & 63;
#pragma unroll
      for (int gate = 0; gate < 4; ++gate) {
        int r = gate * 2 + unit;
        float v = bias_lds[r];
#pragma unroll
        for (int ww = 0; ww < 4; ++ww) v += pbuf[(ww * 8 + r) * 64 + b];
        xp_out[((size_t)(bid * S + s) * 8 + r) * 64 + b] = v;
      }
    }
    __syncthreads();
  }
}

struct XpParams {
  const int* src; const int* tgt;
  const float* enc_emb; const float* dec_emb;
  const float* enc_Wih; const float* enc_bih; const float* enc_bhh;
  const float* dec_Wih; const float* dec_bih; const float* dec_bhh;
  float* xpe; float* xpd;
};

__global__ __launch_bounds__(256) void xp_k(XpParams p) {
  __shared__ __align__(16) float W_lds[8 * EDIM];
  __shared__ float pbuf[32 * 64];
  __shared__ float bias_lds[8];
  const int bid = blockIdx.x;
  if (bid < 256)
    xp_phase(p.src, SENC, SENC, p.enc_emb, p.enc_Wih, p.enc_bih, p.enc_bhh,
             p.xpe, bid, threadIdx.x, W_lds, pbuf, bias_lds);
  else
    xp_phase(p.tgt, 32, TDEC, p.dec_emb, p.dec_Wih, p.dec_bih, p.dec_bhh,
             p.xpd, bid - 256, threadIdx.x, W_lds, pbuf, bias_lds);
}

// ---------------- recurrence (cooperative, custom barrier) ----------------
// Cumulative-counter barrier: generation g's target is NBLK*(g+1); the counter
// is never reset, so no sense reversal is needed. Release on the RMW publishes
// this block's h writes; one acquire fence after the poll invalidates stale L2.
__device__ __forceinline__ void grid_barrier(unsigned* cnt, unsigned target) {
  __syncthreads();
  if (threadIdx.x == 0) {
    __hip_atomic_fetch_add(cnt, 1u, __ATOMIC_RELEASE, __HIP_MEMORY_SCOPE_AGENT);
    while (__hip_atomic_load(cnt, __ATOMIC_RELAXED, __HIP_MEMORY_SCOPE_AGENT) < target)
      __builtin_amdgcn_s_sleep(1);
    __builtin_amdgcn_fence(__ATOMIC_ACQUIRE, "agent");
  }
  __syncthreads();
}

__device__ void recur_phase(const float* Whh, const float* xp, int S, int gen0,
                            int last_phase, int bid, int tid,
                            float* W_lds, float* pbuf, float* c_lds,
                            float*& hp, float*& hn,
                            unsigned short* hs_or_null, unsigned* cnt) {
  const int lane = tid & 63;
  const int w = tid >> 6;
  const int j0 = bid * 2;
  {
    int r = tid >> 5;
    int e0 = (tid & 31) * 16;
    int row_g = (r >> 1) * HDIM + j0 + (r & 1);
    const float* sp = Whh + (size_t)row_g * HDIM + e0;
#pragma unroll
    for (int q = 0; q < 4; ++q)
      *(float4*)&W_lds[r * HDIM + e0 + q * 4] = *(const float4*)(sp + q * 4);
  }
  __syncthreads();
  for (int s = 0; s < S; ++s) {
    const float* hpw = hp + (size_t)w * 128 * 64;
    float acc[8];
#pragma unroll
    for (int r = 0; r < 8; ++r) acc[r] = 0.0f;
    for (int kk = 0; kk < 128; kk += 4) {
      float h0 = hpw[(kk + 0) * 64 + lane];
      float h1 = hpw[(kk + 1) * 64 + lane];
      float h2 = hpw[(kk + 2) * 64 + lane];
      float h3 = hpw[(kk + 3) * 64 + lane];
#pragma unroll
      for (int r = 0; r < 8; ++r) {
        float4 wv = *(const float4*)&W_lds[r * HDIM + w * 128 + kk];
        acc[r] += wv.x * h0 + wv.y * h1 + wv.z * h2 + wv.w * h3;
      }
    }
#pragma unroll
    for (int r = 0; r < 8; ++r) pbuf[(w * 8 + r) * 64 + lane] = acc[r];
    __syncthreads();
    if (tid < 128) {
      int unit = tid >> 6, b = tid & 63;
      float g[4];
#pragma unroll
      for (int gate = 0; gate < 4; ++gate) {
        int r = gate * 2 + unit;
        float v = xp[((size_t)(bid * S + s) * 8 + r) * 64 + b];
#pragma unroll
        for (int ww = 0; ww < 4; ++ww) v += pbuf[(ww * 8 + r) * 64 + b];
        g[gate] = v;
      }
      float c = c_lds[unit * 64 + b];
      float iv = sigf(g[0]), fv = sigf(g[1]);
      float gv = tanhfast(g[2]), ov = sigf(g[3]);
      c = fv * c + iv * gv;
      float h = ov * tanhfast(c);
      c_lds[unit * 64 + b] = c;
      hn[(j0 + unit) * 64 + b] = h;
      if (hs_or_null)
        hs_or_null[((size_t)b * TDEC + s) * HDIM + j0 + unit] = f2bf(h);
    }
    if (!(last_phase && s == S - 1))
      grid_barrier(cnt, (unsigned)(NBLK * (gen0 + s + 1)));
    float* tmp = hp; hp = hn; hn = tmp;
  }
}

struct RecurParams {
  const float* enc_Whh; const float* dec_Whh;
  const float* xpe; const float* xpd;
  float* hTA; float* hTB;
  unsigned short* hs;
  unsigned* cnt;
};

__global__ __launch_bounds__(256, 1) void recur_coop(RecurParams p) {
  __shared__ __align__(16) float W_lds[8 * HDIM];     // 16 KB
  __shared__ float pbuf[32 * 64];                     // 8 KB
  __shared__ float c_lds[2 * 64];
  const int tid = threadIdx.x;
  const int bid = blockIdx.x;
  if (tid < 128) c_lds[tid] = 0.0f;
  __syncthreads();
  float* hp = p.hTA;
  float* hn = p.hTB;
  recur_phase(p.enc_Whh, p.xpe, SENC, 0, 0, bid, tid, W_lds, pbuf, c_lds,
              hp, hn, nullptr, p.cnt);
  recur_phase(p.dec_Whh, p.xpd, TDEC, SENC, 1, bid, tid, W_lds, pbuf, c_lds,
              hp, hn, p.hs, p.cnt);
}

// ---------------- FC head: logits = hs @ fcw^T + b ----------------
__global__ __launch_bounds__(256) void fc_gemm(const unsigned short* __restrict__ A,
                                               const unsigned short* __restrict__ Bm,
                                               const float* __restrict__ bias,
                                               float* __restrict__ out) {
  __shared__ __align__(16) unsigned short As[128 * 32];
  __shared__ __align__(16) unsigned short Bs[128 * 32];
  const int tid = threadIdx.x;
  const int lane = tid & 63;
  const int w = tid >> 6;
  const int m0 = blockIdx.y * 128;
  const int n0 = blockIdx.x * 128;
  const int wm = (w >> 1) * 64;
  const int wn = (w & 1) * 64;
  const int ml = lane & 15;
  const int kq = (lane >> 4) * 8;

  f32x4 acc[4][4] = {};

  for (int k0 = 0; k0 < HDIM; k0 += 32) {
    for (int c = tid; c < 512; c += 256) {
      int row = c >> 2;
      int ko = (c & 3) * 8;
      *(uint4*)&As[c * 8] = *(const uint4*)(A + (size_t)(m0 + row) * HDIM + k0 + ko);
      *(uint4*)&Bs[c * 8] = *(const uint4*)(Bm + (size_t)(n0 + row) * HDIM + k0 + ko);
    }
    __syncthreads();
    bf16x8 fa[4], fb[4];
#pragma unroll
    for (int i = 0; i < 4; ++i)
      fa[i] = *(const bf16x8*)&As[(wm + 16 * i + ml) * 32 + kq];
#pragma unroll
    for (int j = 0; j < 4; ++j)
      fb[j] = *(const bf16x8*)&Bs[(wn + 16 * j + ml) * 32 + kq];
#pragma unroll
    for (int i = 0; i < 4; ++i)
#pragma unroll
      for (int j = 0; j < 4; ++j)
        acc[i][j] = __builtin_amdgcn_mfma_f32_16x16x32_bf16(fa[i], fb[j], acc[i][j], 0, 0, 0);
    __syncthreads();
  }

  const int rq = (lane >> 4) * 4;
#pragma unroll
  for (int j = 0; j < 4; ++j) {
    int n = n0 + wn + 16 * j + ml;
    float bv = bias[n];
#pragma unroll
    for (int i = 0; i < 4; ++i) {
#pragma unroll
      for (int r = 0; r < 4; ++r) {
        int m = m0 + wm + 16 * i + rq + r;
        if (m < MROWS) {
          int b = m / TDEC;
          int t = m - b * TDEC;
          out[((size_t)(b * 32 + t + 1)) * VOCAB + n] = acc[i][j][r] + bv;
        }
      }
    }
  }
}

extern "C" void kernel_launch(void* const* d_in, const int* in_sizes, int n_in,
                              void* d_out, int out_size, void* d_ws, size_t ws_size,
                              hipStream_t stream) {
  (void)in_sizes; (void)n_in; (void)out_size; (void)ws_size;
  const int* src      = (const int*)d_in[0];
  const int* tgt      = (const int*)d_in[1];
  const float* enc_emb = (const float*)d_in[2];
  const float* dec_emb = (const float*)d_in[3];
  const float* enc_Wih = (const float*)d_in[4];
  const float* enc_Whh = (const float*)d_in[5];
  const float* enc_bih = (const float*)d_in[6];
  const float* enc_bhh = (const float*)d_in[7];
  const float* dec_Wih = (const float*)d_in[8];
  const float* dec_Whh = (const float*)d_in[9];
  const float* dec_bih = (const float*)d_in[10];
  const float* dec_bhh = (const float*)d_in[11];
  const float* fc_W    = (const float*)d_in[12];
  const float* fc_b    = (const float*)d_in[13];
  char* ws = (char*)d_ws;
  float* hTA = (float*)(ws + OFF_HTA);
  float* hTB = (float*)(ws + OFF_HTB);
  float* xpe = (float*)(ws + OFF_XPE);
  float* xpd = (float*)(ws + OFF_XPD);
  unsigned short* hs  = (unsigned short*)(ws + OFF_HS);
  unsigned short* fcw = (unsigned short*)(ws + OFF_FCW);
  unsigned* cnt = (unsigned*)(ws + OFF_HS + (size_t)MROWS * HDIM * 2);
  float* out = (float*)d_out;

  hipLaunchKernelGGL(setup_k, dim3(2048), dim3(256), 0, stream, fc_W, fcw, hTA, hs, out);

  XpParams xq = { src, tgt, enc_emb, dec_emb, enc_Wih, enc_bih, enc_bhh,
                  dec_Wih, dec_bih, dec_bhh, xpe, xpd };
  hipLaunchKernelGGL(xp_k, dim3(512), dim3(256), 0, stream, xq);

  RecurParams rp = { enc_Whh, dec_Whh, xpe, xpd, hTA, hTB, hs, cnt };
  void* args[] = { &rp };
  hipLaunchCooperativeKernel((const void*)recur_coop, dim3(NBLK), dim3(256), args, 0, stream);

  hipLaunchKernelGGL(fc_gemm, dim3(VOCAB / 128, MPAD / 128), dim3(256), 0, stream,
                     hs, fcw, fc_b, out);
}